// Round 2
// baseline (787.702 us; speedup 1.0000x reference)
//
#include <hip/hip_runtime.h>

#define T_STEPS 512
#define IN_DIM 28
#define HDIM 128
#define BT 16          // batch rows per block (= MFMA M)
#define NTHREADS 512   // 8 waves

typedef _Float16 f16x8 __attribute__((ext_vector_type(8)));
typedef float f32x4 __attribute__((ext_vector_type(4)));

#if __has_builtin(__builtin_amdgcn_exp2f)
#define EXP2F __builtin_amdgcn_exp2f
#else
#define EXP2F exp2f
#endif
#if __has_builtin(__builtin_amdgcn_rcpf)
#define RCPF __builtin_amdgcn_rcpf
#else
#define RCPF(v) (1.0f / (v))
#endif

__device__ __forceinline__ float fast_sigmoid(float v) {
    return RCPF(1.0f + EXP2F(v * -1.442695041f));
}
__device__ __forceinline__ float fast_tanh(float v) {
    return 2.0f * RCPF(1.0f + EXP2F(v * -2.885390082f)) - 1.0f;
}

// LDS byte map (10240 B total):
//   [0,4096)      h buffer 0   [16 rows][128 f16], rows swizzled ^(row&7)<<4
//   [4096,8192)   h buffer 1
//   [8192,9216)   x stage 0    [16 rows][32 f16],  rows swizzled ^(row&3)<<4
//   [9216,10240)  x stage 1
#define HB0 0
#define HB1 4096
#define XS0 8192
#define XS1 (8192 + 1024)

__global__ __launch_bounds__(NTHREADS, 2) void gru_fused(
    const float* __restrict__ x,     // [B, T, 28]
    const float* __restrict__ w_x,   // [3, 28, 128]
    const float* __restrict__ b_x,   // [3, 128]
    const float* __restrict__ w_h,   // [3, 128, 128]
    const float* __restrict__ b_h,   // [3, 128]
    const float* __restrict__ fc_w,  // [128, 10]
    const float* __restrict__ fc_b,  // [10]
    float* __restrict__ out)         // [B, 10]
{
    const int tid = threadIdx.x;
    const int wv  = tid >> 6;          // wave 0..7
    const int l   = tid & 63;          // lane
    const int lr  = l & 15;            // A-row / C-col within tile
    const int lg  = l >> 4;            // k-group (A/B) / row-group (C)
    const int b0  = blockIdx.x * BT;
    const int col = wv * 16 + lr;      // this lane's output column (0..127)

    __shared__ __align__(16) unsigned char lds[2 * 4096 + 2 * 1024];

    // ---- persistent weight fragments (VGPRs) ----
    // B-frag 16x16x32: lane holds B[k][n], n = col(lane&15), k = kf*32 + lg*8 + e
    f16x8 whf[3][4];
#pragma unroll
    for (int g = 0; g < 3; ++g)
#pragma unroll
        for (int kf = 0; kf < 4; ++kf)
#pragma unroll
            for (int e = 0; e < 8; ++e)
                whf[g][kf][e] = (_Float16)w_h[(g * HDIM + kf * 32 + lg * 8 + e) * HDIM + col];

    f16x8 wxf[3];   // K padded 28 -> 32 with zeros
#pragma unroll
    for (int g = 0; g < 3; ++g)
#pragma unroll
        for (int e = 0; e < 8; ++e) {
            int k = lg * 8 + e;
            wxf[g][e] = (k < IN_DIM) ? (_Float16)w_x[(g * IN_DIM + k) * HDIM + col]
                                     : (_Float16)0.0f;
        }

    // persistent MFMA C-in vectors: bias broadcast over the lane's 4 rows.
    // gates 0,1 only ever use accX+accG, so fold b_x into the h-path bias.
    f32x4 zero4 = {0.0f, 0.0f, 0.0f, 0.0f};
    f32x4 cinitX2, cinitG[3];
    {
        float bx2 = b_x[2 * HDIM + col];
        cinitX2 = (f32x4){bx2, bx2, bx2, bx2};
        float s0 = b_h[0 * HDIM + col] + b_x[0 * HDIM + col];
        float s1 = b_h[1 * HDIM + col] + b_x[1 * HDIM + col];
        float s2 = b_h[2 * HDIM + col];
        cinitG[0] = (f32x4){s0, s0, s0, s0};
        cinitG[1] = (f32x4){s1, s1, s1, s1};
        cinitG[2] = (f32x4){s2, s2, s2, s2};
    }

    // ---- loop-invariant LDS byte offsets ----
    int ha_off[4];
#pragma unroll
    for (int kf = 0; kf < 4; ++kf)
        ha_off[kf] = (lr << 8) + (((kf << 6) + (lg << 4)) ^ ((lr & 7) << 4));
    int wa_off[4];
#pragma unroll
    for (int r = 0; r < 4; ++r) {
        int row = lg * 4 + r;
        wa_off[r] = (row << 8) + ((col << 1) ^ ((row & 7) << 4));
    }
    const int xr_off = lr * 64 + ((lg << 4) ^ ((lr & 3) << 4));

    // x cooperative staging: thread -> (row, k) of the [16][32] stage tile
    const int  xrow_s  = tid >> 5;      // 0..15
    const int  xk      = tid & 31;      // 0..31 (28..31 = zero pad)
    const bool x_valid = (xk < IN_DIM);
    const int  xw_off  = xrow_s * 64 + ((xk << 1) ^ ((xrow_s & 3) << 4));
    const float* gptr  = x + (size_t)(b0 + xrow_s) * (T_STEPS * IN_DIM)
                           + (x_valid ? xk : 0);

    // ---- prologue: zero h(0), stage x(0) ----
    for (int i = tid; i < 1024; i += NTHREADS) ((int*)lds)[i] = 0;  // hb0
    {
        float v0 = x_valid ? gptr[0] : 0.0f;
        *(_Float16*)(lds + XS0 + xw_off) = (_Float16)v0;
    }
    float h_c[4] = {0.0f, 0.0f, 0.0f, 0.0f};  // my (rows, col) slice, fp32
    __syncthreads();

    auto step = [&](int t, int cur) {
        unsigned char* hcur = lds + (cur ? HB1 : HB0);
        unsigned char* hnxt = lds + (cur ? HB0 : HB1);
        unsigned char* xcur = lds + (cur ? XS1 : XS0);
        unsigned char* xnxt = lds + (cur ? XS0 : XS1);

        // issue next-step x prefetch early (hides HBM latency under compute)
        int   tn  = (t + 1 < T_STEPS) ? t + 1 : t;
        float xpf = x_valid ? gptr[(size_t)tn * IN_DIM] : 0.0f;

        // LDS -> A-fragments
        f16x8 xa = *(const f16x8*)(xcur + xr_off);
        f16x8 ha[4];
#pragma unroll
        for (int kf = 0; kf < 4; ++kf)
            ha[kf] = *(const f16x8*)(hcur + ha_off[kf]);

        // gx = x @ w_x (+ b_x[2] only; gates 0,1 bias folded into accG)
        f32x4 accX[3];
        accX[0] = __builtin_amdgcn_mfma_f32_16x16x32_f16(xa, wxf[0], zero4, 0, 0, 0);
        accX[1] = __builtin_amdgcn_mfma_f32_16x16x32_f16(xa, wxf[1], zero4, 0, 0, 0);
        accX[2] = __builtin_amdgcn_mfma_f32_16x16x32_f16(xa, wxf[2], cinitX2, 0, 0, 0);

        // gh = h @ w_h + biases (K=128 -> 4 chained K-steps per gate)
        f32x4 accG[3];
#pragma unroll
        for (int g = 0; g < 3; ++g)
            accG[g] = __builtin_amdgcn_mfma_f32_16x16x32_f16(ha[0], whf[g][0], cinitG[g], 0, 0, 0);
#pragma unroll
        for (int kf = 1; kf < 4; ++kf)
#pragma unroll
            for (int g = 0; g < 3; ++g)
                accG[g] = __builtin_amdgcn_mfma_f32_16x16x32_f16(ha[kf], whf[g][kf], accG[g], 0, 0, 0);

        // gates + state update (C layout: row = lg*4+r, col = col)
#pragma unroll
        for (int r = 0; r < 4; ++r) {
            float rg = fast_sigmoid(accX[0][r] + accG[0][r]);
            float zg = fast_sigmoid(accX[1][r] + accG[1][r]);
            float ng = fast_tanh(accX[2][r] + rg * accG[2][r]);
            h_c[r] = ng + zg * (h_c[r] - ng);   // (1-z)*n + z*h
            *(_Float16*)(hnxt + wa_off[r]) = (_Float16)h_c[r];
        }

        // stage x(t+1) (vmcnt wait lands here, long after issue)
        *(_Float16*)(xnxt + xw_off) = (_Float16)xpf;

        __syncthreads();
    };

    for (int t = 0; t < T_STEPS; t += 2) {
        step(t, 0);
        step(t + 1, 1);
    }

    // ---- final FC: out = h_last @ fc_w + fc_b ----
    float* hf = (float*)lds;  // reuse h buffers: 16*128 fp32 = 8 KiB
#pragma unroll
    for (int r = 0; r < 4; ++r) hf[(lg * 4 + r) * HDIM + col] = h_c[r];
    __syncthreads();

    if (tid < BT * 10) {
        int b = tid / 10, o = tid % 10;
        float s = fc_b[o];
        for (int j = 0; j < HDIM; ++j) s += hf[b * HDIM + j] * fc_w[j * 10 + o];
        out[(size_t)(b0 + b) * 10 + o] = s;
    }
}

extern "C" void kernel_launch(void* const* d_in, const int* in_sizes, int n_in,
                              void* d_out, int out_size, void* d_ws, size_t ws_size,
                              hipStream_t stream) {
    const float* x    = (const float*)d_in[0];
    const float* w_x  = (const float*)d_in[1];
    const float* b_x  = (const float*)d_in[2];
    const float* w_h  = (const float*)d_in[3];
    const float* b_h  = (const float*)d_in[4];
    const float* fc_w = (const float*)d_in[5];
    const float* fc_b = (const float*)d_in[6];
    float* out = (float*)d_out;

    int B = in_sizes[0] / (T_STEPS * IN_DIM);  // 4096
    gru_fused<<<B / BT, NTHREADS, 0, stream>>>(x, w_x, b_x, w_h, b_h, fc_w, fc_b, out);
}

// Round 5
// 675.223 us; speedup vs baseline: 1.1666x; 1.1666x over previous
//
#include <hip/hip_runtime.h>

#define T_STEPS 512
#define IN_DIM 28
#define HDIM 128
#define BT 16          // batch rows per block (= MFMA M)
#define NTHREADS 512   // 8 waves

typedef _Float16 f16x8 __attribute__((ext_vector_type(8)));
typedef __fp16   fp16x2 __attribute__((ext_vector_type(2)));   // cvt_pkrtz return type
typedef float f32x4 __attribute__((ext_vector_type(4)));

#if __has_builtin(__builtin_amdgcn_exp2f)
#define EXP2F __builtin_amdgcn_exp2f
#else
#define EXP2F exp2f
#endif
#if __has_builtin(__builtin_amdgcn_rcpf)
#define RCPF __builtin_amdgcn_rcpf
#else
#define RCPF(v) (1.0f / (v))
#endif

// Bank-swizzle key: rows {r, r+4, r+8, r+12} (one per lg group) map to 4
// DISTINCT keys -> distinct bank groups on the 2B scatter writes.
// (old (row&7) key collided lg=0 with lg=2, lg=1 with lg=3 -> 2.1e7 conflicts)
#define SWZ(r) ((((r) + ((r) >> 3))) & 7)

__device__ __forceinline__ f16x8 cvt_f16x8(f32x4 a, f32x4 b) {
    union { f16x8 v; fp16x2 h[4]; } u;
    u.h[0] = __builtin_amdgcn_cvt_pkrtz(a[0], a[1]);
    u.h[1] = __builtin_amdgcn_cvt_pkrtz(a[2], a[3]);
    u.h[2] = __builtin_amdgcn_cvt_pkrtz(b[0], b[1]);
    u.h[3] = __builtin_amdgcn_cvt_pkrtz(b[2], b[3]);
    return u.v;
}

__global__ __launch_bounds__(NTHREADS, 2) void gru_fused(
    const float* __restrict__ x,     // [B, T, 28]
    const float* __restrict__ w_x,   // [3, 28, 128]
    const float* __restrict__ b_x,   // [3, 128]
    const float* __restrict__ w_h,   // [3, 128, 128]
    const float* __restrict__ b_h,   // [3, 128]
    const float* __restrict__ fc_w,  // [128, 10]
    const float* __restrict__ fc_b,  // [10]
    float* __restrict__ out)         // [B, 10]
{
    const int tid = threadIdx.x;
    const int wv  = tid >> 6;          // wave 0..7
    const int l   = tid & 63;          // lane
    const int lr  = l & 15;            // A-row / C-col within tile
    const int lg  = l >> 4;            // k-group (A/B) / row-group (C)
    const int b0  = blockIdx.x * BT;
    const int col = wv * 16 + lr;      // this lane's output column (0..127)

    // h ping-pong buffers: [16 rows][128 f16], swizzled. 8 KiB.
    __shared__ __align__(16) unsigned char lds[2 * BT * HDIM * 2];

    // ---- persistent weight B-fragments (VGPRs) ----
    // B-frag 16x16x32: lane holds B[k][n], n = col(lane&15), k = kf*32 + lg*8 + e
    f16x8 whf[3][4];
#pragma unroll
    for (int g = 0; g < 3; ++g)
#pragma unroll
        for (int kf = 0; kf < 4; ++kf)
#pragma unroll
            for (int e = 0; e < 8; ++e)
                whf[g][kf][e] = (_Float16)w_h[(g * HDIM + kf * 32 + lg * 8 + e) * HDIM + col];

    f16x8 wxf[3];   // K padded 28 -> 32 with zeros
#pragma unroll
    for (int g = 0; g < 3; ++g)
#pragma unroll
        for (int e = 0; e < 8; ++e) {
            int k = lg * 8 + e;
            wxf[g][e] = (k < IN_DIM) ? (_Float16)w_x[(g * IN_DIM + k) * HDIM + col]
                                     : (_Float16)0.0f;
        }

    // persistent MFMA C-in: biases broadcast over the lane's 4 rows.
    const f32x4 zero4 = {0.0f, 0.0f, 0.0f, 0.0f};
    f32x4 cinitX2, cinitG[3];
    {
        float bx2 = b_x[2 * HDIM + col];
        cinitX2 = (f32x4){bx2, bx2, bx2, bx2};
        float s0 = b_h[0 * HDIM + col] + b_x[0 * HDIM + col];
        float s1 = b_h[1 * HDIM + col] + b_x[1 * HDIM + col];
        float s2 = b_h[2 * HDIM + col];
        cinitG[0] = (f32x4){s0, s0, s0, s0};
        cinitG[1] = (f32x4){s1, s1, s1, s1};
        cinitG[2] = (f32x4){s2, s2, s2, s2};
    }

    // ---- loop-invariant LDS byte offsets (swizzle key on both sides) ----
    int ha_off[4];
#pragma unroll
    for (int kf = 0; kf < 4; ++kf)
        ha_off[kf] = (lr << 8) + (((kf << 6) + (lg << 4)) ^ (SWZ(lr) << 4));
    int wa_off[4];
#pragma unroll
    for (int r = 0; r < 4; ++r) {
        int row = lg * 4 + r;
        wa_off[r] = (row << 8) + ((col << 1) ^ (SWZ(row) << 4));
    }

    // ---- direct per-wave x loads (no LDS staging; 1.8KB/step -> L1-hit) ----
    // lane (lg,lr) holds A-frag elems k = lg*8 + e; lg==3 upper half = pad.
    // OOB FIX: lg==3's xhi (k=28..31) is always discarded via pad_hi, but the
    // load still issues; for batch row 4095 @ t=511 it reads past the end of
    // x -> HSA memory fault (round-4 core dump). Redirect lg==3's hi pointer
    // back onto its own k=24..27 bytes so the dead load stays in-bounds.
    const float* xrow  = x + (size_t)(b0 + lr) * (T_STEPS * IN_DIM) + lg * 8;
    const bool pad_hi  = (lg == 3);
    const float* xrowh = xrow + (pad_hi ? 0 : 4);

    // prologue: zero h(0)
    for (int i = tid; i < BT * HDIM / 2; i += NTHREADS) ((int*)lds)[i] = 0;

    // x(0) -> accXA (projection for t=0), prefetch x(1)
    f32x4 xlo = *(const f32x4*)(xrow);
    f32x4 xhi = *(const f32x4*)(xrowh);
    if (pad_hi) xhi = zero4;
    f16x8 xa0 = cvt_f16x8(xlo, xhi);
    f32x4 accXA[3], accXB[3];
    accXA[0] = __builtin_amdgcn_mfma_f32_16x16x32_f16(xa0, wxf[0], zero4, 0, 0, 0);
    accXA[1] = __builtin_amdgcn_mfma_f32_16x16x32_f16(xa0, wxf[1], zero4, 0, 0, 0);
    accXA[2] = __builtin_amdgcn_mfma_f32_16x16x32_f16(xa0, wxf[2], cinitX2, 0, 0, 0);
    xlo = *(const f32x4*)(xrow + IN_DIM);
    xhi = *(const f32x4*)(xrowh + IN_DIM);

    float h_c[4] = {0.0f, 0.0f, 0.0f, 0.0f};  // my (rows, col) slice, fp32
    __syncthreads();

#define GRU_STEP(ACC_CUR, ACC_NXT, HCUR, HNXT, TPF)                               \
    {                                                                              \
        const unsigned char* hcur = lds + (HCUR);                                  \
        unsigned char* hnxt = lds + (HNXT);                                        \
        f16x8 ha[4];                                                               \
        _Pragma("unroll")                                                          \
        for (int kf = 0; kf < 4; ++kf)                                             \
            ha[kf] = *(const f16x8*)(hcur + ha_off[kf]);                           \
        /* build next-step x A-frag from prefetched regs, then prefetch t+2 */     \
        f32x4 hi_m = pad_hi ? zero4 : xhi;                                         \
        f16x8 xan = cvt_f16x8(xlo, hi_m);                                          \
        {                                                                          \
            int tp = (TPF); if (tp >= T_STEPS) tp = T_STEPS - 1;                   \
            xlo = *(const f32x4*)(xrow + tp * IN_DIM);                             \
            xhi = *(const f32x4*)(xrowh + tp * IN_DIM);                            \
        }                                                                          \
        /* gh = h @ w_h + bias (chain over kf, 3 gates parallel) */                \
        f32x4 accG[3];                                                             \
        _Pragma("unroll")                                                          \
        for (int g = 0; g < 3; ++g)                                                \
            accG[g] = __builtin_amdgcn_mfma_f32_16x16x32_f16(ha[0], whf[g][0], cinitG[g], 0, 0, 0); \
        _Pragma("unroll")                                                          \
        for (int kf = 1; kf < 4; ++kf)                                             \
            _Pragma("unroll")                                                      \
            for (int g = 0; g < 3; ++g)                                            \
                accG[g] = __builtin_amdgcn_mfma_f32_16x16x32_f16(ha[kf], whf[g][kf], accG[g], 0, 0, 0); \
        /* x-projection for NEXT step (independent -> fills MFMA pipe) */          \
        ACC_NXT[0] = __builtin_amdgcn_mfma_f32_16x16x32_f16(xan, wxf[0], zero4, 0, 0, 0);   \
        ACC_NXT[1] = __builtin_amdgcn_mfma_f32_16x16x32_f16(xan, wxf[1], zero4, 0, 0, 0);   \
        ACC_NXT[2] = __builtin_amdgcn_mfma_f32_16x16x32_f16(xan, wxf[2], cinitX2, 0, 0, 0); \
        /* gates: shared-rcp sigmoid pair + tanh; h update; swizzled b16 store */  \
        _Pragma("unroll")                                                          \
        for (int r = 0; r < 4; ++r) {                                              \
            float v0 = ACC_CUR[0][r] + accG[0][r];                                 \
            float v1 = ACC_CUR[1][r] + accG[1][r];                                 \
            float e0 = EXP2F(v0 * -1.442695041f);                                  \
            float e1 = EXP2F(v1 * -1.442695041f);                                  \
            float p0 = 1.0f + e0, p1 = 1.0f + e1;                                  \
            float rd = RCPF(p0 * p1);                                              \
            float rg = p1 * rd;  /* sigmoid(v0) */                                 \
            float zg = p0 * rd;  /* sigmoid(v1) */                                 \
            float q  = ACC_CUR[2][r] + rg * accG[2][r];                            \
            float e2 = EXP2F(q * -2.885390082f);                                   \
            float ng = 2.0f * RCPF(1.0f + e2) - 1.0f;  /* tanh(q) */               \
            h_c[r] = ng + zg * (h_c[r] - ng);                                      \
            *(_Float16*)(hnxt + wa_off[r]) = (_Float16)h_c[r];                     \
        }                                                                          \
        __syncthreads();                                                           \
    }

    for (int t = 0; t < T_STEPS; t += 2) {
        GRU_STEP(accXA, accXB, 0, 4096, t + 2)      // even step t
        GRU_STEP(accXB, accXA, 4096, 0, t + 3)      // odd step t+1
    }
#undef GRU_STEP

    // ---- final FC: out = h_last @ fc_w + fc_b ----
    float* hf = (float*)lds;  // reuse both h buffers: 16*128 fp32 = 8 KiB
#pragma unroll
    for (int r = 0; r < 4; ++r) hf[(lg * 4 + r) * HDIM + col] = h_c[r];
    __syncthreads();

    if (tid < BT * 10) {
        int b = tid / 10, o = tid % 10;
        float s = fc_b[o];
        for (int j = 0; j < HDIM; ++j) s += hf[b * HDIM + j] * fc_w[j * 10 + o];
        out[(size_t)(b0 + b) * 10 + o] = s;
    }
}

extern "C" void kernel_launch(void* const* d_in, const int* in_sizes, int n_in,
                              void* d_out, int out_size, void* d_ws, size_t ws_size,
                              hipStream_t stream) {
    const float* x    = (const float*)d_in[0];
    const float* w_x  = (const float*)d_in[1];
    const float* b_x  = (const float*)d_in[2];
    const float* w_h  = (const float*)d_in[3];
    const float* b_h  = (const float*)d_in[4];
    const float* fc_w = (const float*)d_in[5];
    const float* fc_b = (const float*)d_in[6];
    float* out = (float*)d_out;

    int B = in_sizes[0] / (T_STEPS * IN_DIM);  // 4096
    gru_fused<<<B / BT, NTHREADS, 0, stream>>>(x, w_x, b_x, w_h, b_h, fc_w, fc_b, out);
}